// Round 1
// baseline (522.988 us; speedup 1.0000x reference)
//
#include <hip/hip_runtime.h>
#include <cstdint>

#define EPSF 1e-5f

// workspace layout (float offsets)
#define WS_MS 0        // M_s  [k=84][o=64]
#define WS_MT 5376     // M_t  [k=84][o=64]
#define WS_B0 10752    // bias0 [64]  (folded ps-BN bias)
#define WS_WC 10816    // conv w folded [i=9][o=64]
#define WS_BC 11392    // conv bias folded [64]
#define WS_WF 11456    // W_fu folded [c=128][o=64]
#define WS_BF 19648    // fu bias folded [64]
#define WS_TOTAL 19712

__global__ __launch_bounds__(64) void stem_prep(
    const float* __restrict__ W_ssig, const float* __restrict__ b_ssig,
    const float* __restrict__ W_tsig, const float* __restrict__ b_tsig,
    const float* __restrict__ W_raw,  const float* __restrict__ b_raw,
    const float* __restrict__ W_ps,   const float* __restrict__ b_ps,
    const float* __restrict__ W_fu,   const float* __restrict__ b_fu,
    const float* __restrict__ g_raw, const float* __restrict__ be_raw,
    const float* __restrict__ m_raw, const float* __restrict__ v_raw,
    const float* __restrict__ g_ps,  const float* __restrict__ be_ps,
    const float* __restrict__ m_ps,  const float* __restrict__ v_ps,
    const float* __restrict__ g_fu,  const float* __restrict__ be_fu,
    const float* __restrict__ m_fu,  const float* __restrict__ v_fu,
    float* __restrict__ ws)
{
    const int o = threadIdx.x;        // 0..63 output channel
    const int bid = blockIdx.x;
    if (bid < 84) {
        const int k = bid;
        const float sps = g_ps[o] / sqrtf(v_ps[o] + EPSF);
        float accs = 0.f, acct = 0.f;
        for (int c = 0; c < 64; ++c) {
            accs = fmaf(W_ps[o*128 + c],      W_ssig[c*84 + k], accs);
            acct = fmaf(W_ps[o*128 + 64 + c], W_tsig[c*84 + k], acct);
        }
        ws[WS_MS + k*64 + o] = accs * sps;
        ws[WS_MT + k*64 + o] = acct * sps;
    } else if (bid == 84) {
        const float sps = g_ps[o] / sqrtf(v_ps[o] + EPSF);
        float acc = b_ps[o] - m_ps[o];
        for (int c = 0; c < 64; ++c) {
            acc = fmaf(W_ps[o*128 + c],      b_ssig[c], acc);
            acc = fmaf(W_ps[o*128 + 64 + c], b_tsig[c], acc);
        }
        ws[WS_B0 + o] = acc * sps + be_ps[o];
        const float sraw = g_raw[o] / sqrtf(v_raw[o] + EPSF);
        ws[WS_BC + o] = (b_raw[o] - m_raw[o]) * sraw + be_raw[o];
        const float sfu = g_fu[o] / sqrtf(v_fu[o] + EPSF);
        ws[WS_BF + o] = (b_fu[o] - m_fu[o]) * sfu + be_fu[o];
    } else if (bid < 94) {
        const int i = bid - 85;       // 0..8 = ci*3+kt
        const float sraw = g_raw[o] / sqrtf(v_raw[o] + EPSF);
        ws[WS_WC + i*64 + o] = W_raw[o*9 + i] * sraw;
    } else {
        const int c = bid - 94;       // 0..127
        const float sfu = g_fu[o] / sqrtf(v_fu[o] + EPSF);
        ws[WS_WF + c*64 + o] = W_fu[o*128 + c] * sfu;
    }
}

// one depth-3 signature step with increment d[4]; uses OLD S1,S2 (order matters)
__device__ __forceinline__ void sig_step(float S1[4], float S2[16], float S3[64], const float d[4])
{
    float e2[16];
#pragma unroll
    for (int i = 0; i < 4; ++i) {
        const float dh = 0.5f * d[i];
#pragma unroll
        for (int j = 0; j < 4; ++j) e2[i*4+j] = dh * d[j];
    }
    float f[4];
#pragma unroll
    for (int i = 0; i < 4; ++i) f[i] = fmaf(d[i], (1.f/3.f), S1[i]);  // S1 + d/3
#pragma unroll
    for (int i = 0; i < 4; ++i) {
#pragma unroll
        for (int j = 0; j < 4; ++j) {
            const float s2 = S2[i*4+j];
            const float fi = f[i];
#pragma unroll
            for (int k = 0; k < 4; ++k)
                S3[(i*4+j)*4+k] = fmaf(s2, d[k], fmaf(fi, e2[j*4+k], S3[(i*4+j)*4+k]));
        }
    }
#pragma unroll
    for (int i = 0; i < 4; ++i) {
#pragma unroll
        for (int j = 0; j < 4; ++j) S2[i*4+j] = fmaf(S1[i], d[j], S2[i*4+j] + e2[i*4+j]);
    }
#pragma unroll
    for (int i = 0; i < 4; ++i) S1[i] += d[i];
}

// grid: (T/128, J, B); block 128; thread = one column (b,j,t), lane varies t (coalesced)
__global__ __launch_bounds__(128, 1) void stem_main(
    const float* __restrict__ x, const int* __restrict__ path,
    const float* __restrict__ ws, float* __restrict__ out)
{
    __shared__ float sigbuf[128][85];   // 85: gcd(85,32)=1 -> conflict-free; private per thread, no barriers
    const int tid = threadIdx.x;
    const int t   = blockIdx.x * 128 + tid;
    const int j   = blockIdx.y;
    const int b   = blockIdx.z;
    const float* xb = x + (size_t)b * (3*64*256);
    float* srow = &sigbuf[tid][0];

    float S1[4], S2[16], S3[64];
#pragma unroll
    for (int i=0;i<4;i++)  S1[i]=0.f;
#pragma unroll
    for (int i=0;i<16;i++) S2[i]=0.f;
#pragma unroll
    for (int i=0;i<64;i++) S3[i]=0.f;

    // ---- spatial signature: points s=0..4, channels (x[b,c,path[j,s],t], s/4) ----
    {
        float pr0=0.f, pr1=0.f, pr2=0.f, pr3=0.f;
        int jp = path[j*5 + 0];
        float n0 = xb[(0*64 + jp)*256 + t];
        float n1 = xb[(1*64 + jp)*256 + t];
        float n2 = xb[(2*64 + jp)*256 + t];
#pragma unroll 1
        for (int s = 0; s < 5; ++s) {
            const float p0 = n0, p1 = n1, p2 = n2;
            const float p3 = (float)s * 0.25f;
            const int sn = (s < 4) ? s + 1 : 4;          // prefetch next point
            jp = path[j*5 + sn];
            n0 = xb[(0*64 + jp)*256 + t];
            n1 = xb[(1*64 + jp)*256 + t];
            n2 = xb[(2*64 + jp)*256 + t];
            const float d[4] = {p0-pr0, p1-pr1, p2-pr2, p3-pr3};
            pr0=p0; pr1=p1; pr2=p2; pr3=p3;
            sig_step(S1, S2, S3, d);
        }
    }
#pragma unroll
    for (int i=0;i<4;i++)  srow[i]     = S1[i];
#pragma unroll
    for (int i=0;i<16;i++) srow[4+i]  = S2[i];
#pragma unroll
    for (int i=0;i<64;i++) srow[20+i] = S3[i];

    // acc = bias0 + M_s^T * sigma_s
    float acc[64];
#pragma unroll
    for (int o=0;o<64;o++) acc[o] = ws[WS_B0 + o];
#pragma unroll 1
    for (int k=0;k<84;k++) {
        const float sv = srow[k];
        const float* w = ws + WS_MS + k*64;    // wave-uniform -> scalar loads
#pragma unroll
        for (int o=0;o<64;o++) acc[o] = fmaf(sv, w[o], acc[o]);
    }

    // ---- temporal signature: the reference's reshape SCRAMBLES (T_LEN,J)->(J,T_LEN):
    // point k reads joint (j*7+k)%64 at time clamp(t + (j*7+k)/64 - 3), time-chan k/6 ----
#pragma unroll
    for (int i=0;i<4;i++)  S1[i]=0.f;
#pragma unroll
    for (int i=0;i<16;i++) S2[i]=0.f;
#pragma unroll
    for (int i=0;i<64;i++) S3[i]=0.f;
    {
        float pr0=0.f, pr1=0.f, pr2=0.f, pr3=0.f;
        int idx = j*7;
        int jsrc = idx & 63, tl = idx >> 6;
        int ts0 = min(max(t + tl - 3, 0), 255);
        float n0 = xb[(0*64 + jsrc)*256 + ts0];
        float n1 = xb[(1*64 + jsrc)*256 + ts0];
        float n2 = xb[(2*64 + jsrc)*256 + ts0];
#pragma unroll 1
        for (int k=0;k<7;++k) {
            const float p0=n0, p1=n1, p2=n2;
            const float p3 = (float)k * (1.f/6.f);
            const int kn = (k<6)? k+1 : 6;
            idx = j*7 + kn; jsrc = idx & 63; tl = idx >> 6;
            const int tsn = min(max(t + tl - 3, 0), 255);
            n0 = xb[(0*64 + jsrc)*256 + tsn];
            n1 = xb[(1*64 + jsrc)*256 + tsn];
            n2 = xb[(2*64 + jsrc)*256 + tsn];
            const float d[4] = {p0-pr0, p1-pr1, p2-pr2, p3-pr3};
            pr0=p0; pr1=p1; pr2=p2; pr3=p3;
            sig_step(S1, S2, S3, d);
        }
    }
#pragma unroll
    for (int i=0;i<4;i++)  srow[i]     = S1[i];
#pragma unroll
    for (int i=0;i<16;i++) srow[4+i]  = S2[i];
#pragma unroll
    for (int i=0;i<64;i++) srow[20+i] = S3[i];
#pragma unroll 1
    for (int k=0;k<84;k++) {
        const float sv = srow[k];
        const float* w = ws + WS_MT + k*64;
#pragma unroll
        for (int o=0;o<64;o++) acc[o] = fmaf(sv, w[o], acc[o]);
    }

    // ps BN+ReLU (folded) -> sig column; stash to LDS for runtime-indexed reuse
#pragma unroll
    for (int o=0;o<64;o++) srow[o] = fmaxf(acc[o], 0.f);

    // final: acc = bias_f + Wf[64+c]^T sigcol + Wf[c]^T relu(conv_c)
#pragma unroll
    for (int o=0;o<64;o++) acc[o] = ws[WS_BF + o];
#pragma unroll 1
    for (int c=0;c<64;c++) {
        const float sv = srow[c];
        const float* w = ws + WS_WF + (64 + c)*64;
#pragma unroll
        for (int o=0;o<64;o++) acc[o] = fmaf(sv, w[o], acc[o]);
    }

    // conv half, fused: compute relu(conv[c]) one at a time (zero-pad in T)
    float xv[9];
#pragma unroll
    for (int ci=0; ci<3; ++ci) {
        const float* xr = xb + (ci*64 + j)*256;
        xv[ci*3+0] = (t >= 1)   ? xr[t-1] : 0.f;
        xv[ci*3+1] = xr[t];
        xv[ci*3+2] = (t <= 254) ? xr[t+1] : 0.f;
    }
#pragma unroll 1
    for (int c=0;c<64;c++) {
        float cv = ws[WS_BC + c];
#pragma unroll
        for (int i=0;i<9;i++) cv = fmaf(xv[i], ws[WS_WC + i*64 + c], cv);
        cv = fmaxf(cv, 0.f);
        const float* w = ws + WS_WF + c*64;
#pragma unroll
        for (int o=0;o<64;o++) acc[o] = fmaf(cv, w[o], acc[o]);
    }

    // fu BN+ReLU (folded) and write out[b][o][j][t]
    float* ob = out + ((size_t)b*64*64 + (size_t)j)*256 + t;
#pragma unroll
    for (int o=0;o<64;o++) ob[(size_t)o*(64*256)] = fmaxf(acc[o], 0.f);
}

extern "C" void kernel_launch(void* const* d_in, const int* in_sizes, int n_in,
                              void* d_out, int out_size, void* d_ws, size_t ws_size,
                              hipStream_t stream)
{
    const float* x      = (const float*)d_in[0];
    const int*   path   = (const int*)  d_in[1];
    const float* W_ssig = (const float*)d_in[2];
    const float* b_ssig = (const float*)d_in[3];
    const float* W_tsig = (const float*)d_in[4];
    const float* b_tsig = (const float*)d_in[5];
    const float* W_raw  = (const float*)d_in[6];
    const float* b_raw  = (const float*)d_in[7];
    const float* W_ps   = (const float*)d_in[8];
    const float* b_ps   = (const float*)d_in[9];
    const float* W_fu   = (const float*)d_in[10];
    const float* b_fu   = (const float*)d_in[11];
    const float* g_raw  = (const float*)d_in[12];
    const float* be_raw = (const float*)d_in[13];
    const float* m_raw  = (const float*)d_in[14];
    const float* v_raw  = (const float*)d_in[15];
    const float* g_ps   = (const float*)d_in[16];
    const float* be_ps  = (const float*)d_in[17];
    const float* m_ps   = (const float*)d_in[18];
    const float* v_ps   = (const float*)d_in[19];
    const float* g_fu   = (const float*)d_in[20];
    const float* be_fu  = (const float*)d_in[21];
    const float* m_fu   = (const float*)d_in[22];
    const float* v_fu   = (const float*)d_in[23];
    float* out = (float*)d_out;
    float* ws  = (float*)d_ws;

    stem_prep<<<222, 64, 0, stream>>>(W_ssig, b_ssig, W_tsig, b_tsig, W_raw, b_raw,
                                      W_ps, b_ps, W_fu, b_fu,
                                      g_raw, be_raw, m_raw, v_raw,
                                      g_ps, be_ps, m_ps, v_ps,
                                      g_fu, be_fu, m_fu, v_fu, ws);

    dim3 grid(256/128, 64, 32);   // (t-chunks, J, B)
    stem_main<<<grid, 128, 0, stream>>>(x, path, ws, out);
}